// Round 1
// 560.303 us; speedup vs baseline: 1.3577x; 1.3577x over previous
//
#include <hip/hip_runtime.h>
#include <hip/hip_bf16.h>

typedef __attribute__((ext_vector_type(8))) short short8;
typedef __attribute__((ext_vector_type(4))) float f32x4;
typedef __attribute__((ext_vector_type(4))) unsigned short ushort4v;
typedef __attribute__((ext_vector_type(4))) float float4v;

#define NB 2
#define NS 4096
#define ND 1024
#define NH 16
#define NHD 64

__device__ __forceinline__ unsigned short f2bf(float x) {
    union { float f; unsigned u; } v; v.f = x;
    unsigned r = v.u + 0x7FFFu + ((v.u >> 16) & 1u);
    return (unsigned short)(r >> 16);
}
__device__ __forceinline__ float bf2f(unsigned short u) {
    union { float f; unsigned u; } v; v.u = ((unsigned)u) << 16;
    return v.f;
}

// async global->LDS, 16B per lane. LDS dest = wave-uniform base + lane*16.
__device__ __forceinline__ void gload_lds16(const unsigned short* g, unsigned short* l) {
    __builtin_amdgcn_global_load_lds(
        (const __attribute__((address_space(1))) void*)g,
        (__attribute__((address_space(3))) void*)l,
        16, 0, 0);
}

__global__ void rope_table_kernel(float* __restrict__ cosT, float* __restrict__ sinT) {
    int i = blockIdx.x * blockDim.x + threadIdx.x;  // [0, NS*32)
    int p = i & 31, s = i >> 5;
    float theta = exp2f(-(float)(2 * p) * (13.287712379549449f / 64.0f));  // 10000^(-2p/64)
    float ang = (float)s * theta;
    float sv, cv;
    sincosf(ang, &sv, &cv);
    cosT[i] = cv; sinT[i] = sv;
}

// fp32 -> bf16 elementwise cast, 8 elems/thread (32B read, 16B write).
__global__ void cast_bf16_kernel(const float* __restrict__ in, unsigned short* __restrict__ out, int n8) {
    int i = blockIdx.x * blockDim.x + threadIdx.x;
    if (i >= n8) return;
    float4v a0 = *(const float4v*)(&in[(size_t)i * 8]);
    float4v a1 = *(const float4v*)(&in[(size_t)i * 8 + 4]);
    short8 s8;
    s8[0] = (short)f2bf(a0.x); s8[1] = (short)f2bf(a0.y);
    s8[2] = (short)f2bf(a0.z); s8[3] = (short)f2bf(a0.w);
    s8[4] = (short)f2bf(a1.x); s8[5] = (short)f2bf(a1.y);
    s8[6] = (short)f2bf(a1.z); s8[7] = (short)f2bf(a1.w);
    *(short8*)(&out[(size_t)i * 8]) = s8;
}

// C = A @ W^T + bias. A: [8192][1024] bf16. W: [1024][1024] bf16 row-major.
// m97 structure: 128x128 tile, BK=32, linear LDS (NO padding - required by
// global_load_lds), width-16 global_load_lds staging, ds_read_b128 fragments.
// EPI 0: plain -> out float32 row-major [8192][1024]  (d_out is fp32!)
// EPI 1: RoPE  -> out [B,H,S,HD] bf16
// EPI 2: V^T   -> out [B,H,HD,S] bf16
template<int EPI>
__global__ __launch_bounds__(256, 2) void gemm_kernel(
    const unsigned short* __restrict__ A,
    const unsigned short* __restrict__ Wb,
    const float* __restrict__ bias,
    void* __restrict__ outv,
    const float* __restrict__ cosT,
    const float* __restrict__ sinT)
{
    __shared__ unsigned short As[128 * 32];  // linear: row stride 32 (64B)
    __shared__ unsigned short Bs[128 * 32];
    const int t = threadIdx.x;
    const int wave = t >> 6, lane = t & 63;
    const int quad = lane >> 4, l15 = lane & 15;
    const int wm = (wave & 1) * 64, wn = (wave >> 1) * 64;
    const int m0 = blockIdx.y * 128, n0 = blockIdx.x * 128;

    f32x4 acc[4][4];
#pragma unroll
    for (int i = 0; i < 4; i++)
#pragma unroll
        for (int j = 0; j < 4; j++)
            acc[i][j] = f32x4{0.f, 0.f, 0.f, 0.f};

    for (int k0 = 0; k0 < ND; k0 += 32) {
        // stage: idx = p*256 + t; row = idx>>2, col = (idx&3)*8 elems.
        // LDS linear dest (idx*8 elems) == row*32 + col, matches lane order.
#pragma unroll
        for (int p = 0; p < 2; p++) {
            int idx = p * 256 + t;
            int r = idx >> 2, c = (idx & 3) * 8;
            unsigned short* ldsA = &As[(size_t)(p * 256 + wave * 64) * 8];
            unsigned short* ldsB = &Bs[(size_t)(p * 256 + wave * 64) * 8];
            gload_lds16(&A[(size_t)(m0 + r) * ND + k0 + c], ldsA);
            gload_lds16(&Wb[(size_t)(n0 + r) * ND + k0 + c], ldsB);
        }
        __syncthreads();  // compiler emits vmcnt(0) drain here

        short8 af[4], bfr[4];
#pragma unroll
        for (int mt = 0; mt < 4; mt++)
            af[mt] = *(const short8*)(&As[(wm + mt * 16 + l15) * 32 + quad * 8]);
#pragma unroll
        for (int nt = 0; nt < 4; nt++)
            bfr[nt] = *(const short8*)(&Bs[(wn + nt * 16 + l15) * 32 + quad * 8]);
#pragma unroll
        for (int mt = 0; mt < 4; mt++)
#pragma unroll
            for (int nt = 0; nt < 4; nt++) {
                if (EPI == 0)
                    acc[mt][nt] = __builtin_amdgcn_mfma_f32_16x16x32_bf16(bfr[nt], af[mt], acc[mt][nt], 0, 0, 0);
                else
                    acc[mt][nt] = __builtin_amdgcn_mfma_f32_16x16x32_bf16(af[mt], bfr[nt], acc[mt][nt], 0, 0, 0);
            }
        __syncthreads();
    }

    if (EPI == 0) {
        // operands swapped: D[m=W-row -> quad*4+r][n=seq -> l15]; fp32 output
        float* out = (float*)outv;
#pragma unroll
        for (int mt = 0; mt < 4; mt++) {
            int gm = m0 + wm + mt * 16 + l15;  // seq row
#pragma unroll
            for (int nt = 0; nt < 4; nt++) {
                int gn0 = n0 + wn + nt * 16 + quad * 4;  // feature
                float4v fv;
#pragma unroll
                for (int r = 0; r < 4; r++)
                    fv[r] = acc[mt][nt][r] + bias[gn0 + r];
                *(float4v*)(&out[(size_t)gm * ND + gn0]) = fv;
            }
        }
    } else if (EPI == 1) {
        // D[m=seq -> quad*4+r][n=feature -> l15]
        unsigned short* out = (unsigned short*)outv;
#pragma unroll
        for (int nt = 0; nt < 4; nt++) {
            int gn = n0 + wn + nt * 16 + l15;
            int h = gn >> 6, hd = gn & 63, pr = hd >> 1, im = gn & 1;
            float bv = bias[gn];
#pragma unroll
            for (int mt = 0; mt < 4; mt++) {
                int gm0 = m0 + wm + mt * 16 + quad * 4;
#pragma unroll
                for (int r = 0; r < 4; r++) {
                    int gm = gm0 + r;
                    int b = gm >> 12, s = gm & 4095;
                    float v = acc[mt][nt][r] + bv;
                    float pv = __shfl_xor(v, 1, 64);  // partner feature gn^1, same seq
                    float cv = cosT[s * 32 + pr], sv = sinT[s * 32 + pr];
                    float o = im ? (pv * sv + v * cv) : (v * cv - pv * sv);
                    out[((size_t)(b * NH + h) * NS + s) * NHD + hd] = f2bf(o);
                }
            }
        }
    } else {
        // V^T: out[((b*H+h)*HD+hd)*S + s]
        unsigned short* out = (unsigned short*)outv;
#pragma unroll
        for (int nt = 0; nt < 4; nt++) {
            int gn = n0 + wn + nt * 16 + l15;
            int h = gn >> 6, hd = gn & 63;
            float bv = bias[gn];
#pragma unroll
            for (int mt = 0; mt < 4; mt++) {
                int gm0 = m0 + wm + mt * 16 + quad * 4;
                int b = gm0 >> 12, s0 = gm0 & 4095;
                ushort4v pk;
#pragma unroll
                for (int r = 0; r < 4; r++)
                    pk[r] = f2bf(acc[mt][nt][r] + bv);
                *(ushort4v*)(&out[((size_t)(b * NH + h) * NHD + hd) * NS + s0]) = pk;
            }
        }
    }
}

// Flash attention. Qr,Kr: [BH][S][64] bf16 (RoPE applied). Vt: [BH][64][S] bf16.
// Yatt: [B*S][1024] bf16. Block: 128 q-rows of one (b,h); wave owns 32 q-rows.
// S^T = K.Q^T (softmax axis = C rows -> in-lane + xor16/32); O^T += V^T.P^T via LDS.
__global__ __launch_bounds__(256, 2) void flash_kernel(
    const unsigned short* __restrict__ Qr,
    const unsigned short* __restrict__ Kr,
    const unsigned short* __restrict__ Vt,
    unsigned short* __restrict__ Yatt)
{
    __shared__ unsigned short Ks[128 * 72];    // pad 64->72
    __shared__ unsigned short Vs[64 * 136];    // pad 128->136
    __shared__ unsigned short Pw[4][32 * 136]; // per-wave P [qrow][key]
    const int t = threadIdx.x;
    const int wave = t >> 6, lane = t & 63;
    const int quad = lane >> 4, l15 = lane & 15;
    const int bh = blockIdx.y;
    const int qb = blockIdx.x * 128;
    const int wq = wave * 32;
    const size_t base = (size_t)bh * NS * NHD;

    short8 qf[2][2];
#pragma unroll
    for (int nt = 0; nt < 2; nt++)
#pragma unroll
        for (int kk = 0; kk < 2; kk++)
            qf[nt][kk] = *(const short8*)(&Qr[base + (size_t)(qb + wq + nt * 16 + l15) * NHD + kk * 32 + quad * 8]);

    f32x4 accO[4][2];
#pragma unroll
    for (int i = 0; i < 4; i++)
#pragma unroll
        for (int j = 0; j < 2; j++)
            accO[i][j] = f32x4{0.f, 0.f, 0.f, 0.f};
    float mrow[2] = {-1e30f, -1e30f};
    float lrow[2] = {0.f, 0.f};

    for (int j0 = 0; j0 < NS; j0 += 128) {
#pragma unroll
        for (int p = 0; p < 4; p++) {
            int idx = p * 256 + t;
            { int r = idx >> 3, c = (idx & 7) * 8;
              *(short8*)(&Ks[r * 72 + c]) = *(const short8*)(&Kr[base + (size_t)(j0 + r) * NHD + c]); }
            { int r = idx >> 4, c = (idx & 15) * 8;
              *(short8*)(&Vs[r * 136 + c]) = *(const short8*)(&Vt[(size_t)(bh * NHD + r) * NS + j0 + c]); }
        }
        __syncthreads();

        f32x4 sa[8][2];
#pragma unroll
        for (int mt = 0; mt < 8; mt++)
#pragma unroll
            for (int nt = 0; nt < 2; nt++)
                sa[mt][nt] = f32x4{0.f, 0.f, 0.f, 0.f};
#pragma unroll
        for (int kk = 0; kk < 2; kk++)
#pragma unroll
            for (int mt = 0; mt < 8; mt++) {
                short8 ak = *(const short8*)(&Ks[(mt * 16 + l15) * 72 + kk * 32 + quad * 8]);
#pragma unroll
                for (int nt = 0; nt < 2; nt++)
                    sa[mt][nt] = __builtin_amdgcn_mfma_f32_16x16x32_bf16(ak, qf[nt][kk], sa[mt][nt], 0, 0, 0);
            }

#pragma unroll
        for (int nt = 0; nt < 2; nt++) {
            float mx = -1e30f;
#pragma unroll
            for (int mt = 0; mt < 8; mt++)
#pragma unroll
                for (int r = 0; r < 4; r++)
                    mx = fmaxf(mx, sa[mt][nt][r]);
            mx = fmaxf(mx, __shfl_xor(mx, 16, 64));
            mx = fmaxf(mx, __shfl_xor(mx, 32, 64));
            mx *= 0.125f;  // 1/sqrt(64)
            float mnew = fmaxf(mrow[nt], mx);
            float alpha = __expf(mrow[nt] - mnew);
            float lsum = 0.f;
#pragma unroll
            for (int mt = 0; mt < 8; mt++) {
                ushort4v pk;
#pragma unroll
                for (int r = 0; r < 4; r++) {
                    float pv = __expf(sa[mt][nt][r] * 0.125f - mnew);
                    unsigned short u = f2bf(pv);
                    pk[r] = u;
                    lsum += bf2f(u);  // sum the quantized P for consistency
                }
                *(ushort4v*)(&Pw[wave][(nt * 16 + l15) * 136 + mt * 16 + quad * 4]) = pk;
            }
            lsum += __shfl_xor(lsum, 16, 64);
            lsum += __shfl_xor(lsum, 32, 64);
            lrow[nt] = lrow[nt] * alpha + lsum;
            mrow[nt] = mnew;
#pragma unroll
            for (int mt2 = 0; mt2 < 4; mt2++)
#pragma unroll
                for (int r = 0; r < 4; r++)
                    accO[mt2][nt][r] *= alpha;
        }
        __syncthreads();

#pragma unroll
        for (int kk2 = 0; kk2 < 4; kk2++) {
            short8 av[4], bp[2];
#pragma unroll
            for (int mt2 = 0; mt2 < 4; mt2++)
                av[mt2] = *(const short8*)(&Vs[(mt2 * 16 + l15) * 136 + kk2 * 32 + quad * 8]);
#pragma unroll
            for (int nt = 0; nt < 2; nt++)
                bp[nt] = *(const short8*)(&Pw[wave][(nt * 16 + l15) * 136 + kk2 * 32 + quad * 8]);
#pragma unroll
            for (int mt2 = 0; mt2 < 4; mt2++)
#pragma unroll
                for (int nt = 0; nt < 2; nt++)
                    accO[mt2][nt] = __builtin_amdgcn_mfma_f32_16x16x32_bf16(av[mt2], bp[nt], accO[mt2][nt], 0, 0, 0);
        }
        __syncthreads();
    }

    int b = bh >> 4, h = bh & 15;
#pragma unroll
    for (int nt = 0; nt < 2; nt++) {
        float rl = 1.f / lrow[nt];
        int s = qb + wq + nt * 16 + l15;
#pragma unroll
        for (int mt2 = 0; mt2 < 4; mt2++) {
            ushort4v pk;
#pragma unroll
            for (int r = 0; r < 4; r++)
                pk[r] = f2bf(accO[mt2][nt][r] * rl);
            *(ushort4v*)(&Yatt[((size_t)(b * NS + s)) * ND + h * NHD + mt2 * 16 + quad * 4]) = pk;
        }
    }
}

extern "C" void kernel_launch(void* const* d_in, const int* in_sizes, int n_in,
                              void* d_out, int out_size, void* d_ws, size_t ws_size,
                              hipStream_t stream) {
    // dict order (contractual): consulta, chave, valor, Wq, bq, Wk, bk, Wv, bv, Wo, bo
    const float* consulta = (const float*)d_in[0];
    const float* chave    = (const float*)d_in[1];
    const float* valor    = (const float*)d_in[2];
    const float* Wq = (const float*)d_in[3];
    const float* bq = (const float*)d_in[4];
    const float* Wk = (const float*)d_in[5];
    const float* bk = (const float*)d_in[6];
    const float* Wv = (const float*)d_in[7];
    const float* bv = (const float*)d_in[8];
    const float* Wo = (const float*)d_in[9];
    const float* bo = (const float*)d_in[10];

    const size_t NX = (size_t)8192 * 1024;

    float* cosT = (float*)d_ws;
    float* sinT = cosT + (size_t)NS * 32;
    unsigned short* Qrb = (unsigned short*)(sinT + (size_t)NS * 32);
    unsigned short* Krb = Qrb + NX;
    unsigned short* Vtb = Krb + NX;
    unsigned short* Yat = Vtb + NX;
    unsigned short* Abf = Yat + NX;            // bf16 activation staging (reused)
    unsigned short* Wbf = Abf + NX;            // bf16 weight staging (reused)

    rope_table_kernel<<<NS * 32 / 256, 256, 0, stream>>>(cosT, sinT);

    const int ACT8 = (int)(NX / 8);   // 1048576 vec8 chunks
    const int W8 = ND * ND / 8;       // 131072

    dim3 ggrid(8, 64);

    cast_bf16_kernel<<<ACT8 / 256, 256, 0, stream>>>(consulta, Abf, ACT8);
    cast_bf16_kernel<<<W8 / 256, 256, 0, stream>>>(Wq, Wbf, W8);
    gemm_kernel<1><<<ggrid, 256, 0, stream>>>(Abf, Wbf, bq, Qrb, cosT, sinT);

    cast_bf16_kernel<<<ACT8 / 256, 256, 0, stream>>>(chave, Abf, ACT8);
    cast_bf16_kernel<<<W8 / 256, 256, 0, stream>>>(Wk, Wbf, W8);
    gemm_kernel<1><<<ggrid, 256, 0, stream>>>(Abf, Wbf, bk, Krb, cosT, sinT);

    cast_bf16_kernel<<<ACT8 / 256, 256, 0, stream>>>(valor, Abf, ACT8);
    cast_bf16_kernel<<<W8 / 256, 256, 0, stream>>>(Wv, Wbf, W8);
    gemm_kernel<2><<<ggrid, 256, 0, stream>>>(Abf, Wbf, bv, Vtb, cosT, sinT);

    flash_kernel<<<dim3(32, 32), 256, 0, stream>>>(Qrb, Krb, Vtb, Yat);

    // d_out is FLOAT32 (reference output dtype)
    cast_bf16_kernel<<<W8 / 256, 256, 0, stream>>>(Wo, Wbf, W8);
    gemm_kernel<0><<<ggrid, 256, 0, stream>>>(Yat, Wbf, bo, d_out, cosT, sinT);
}